// Round 1
// baseline (335.574 us; speedup 1.0000x reference)
//
#include <hip/hip_runtime.h>
#include <stdint.h>

#define HH 1024
#define WW 2048
#define HWC (HH * WW)
#define NC 19
#define WP 2080          // padded width: 16 zero cols each side
#define RAD 16
static constexpr float INV_LN19 = 1.0f / 2.9444389791664403f;

static __device__ __forceinline__ int imin(int a, int b) { return a < b ? a : b; }
static __device__ __forceinline__ int imax(int a, int b) { return a > b ? a : b; }

// ---------------- K1: softmax entropy + argmax, 4 pixels/thread ----------------
__global__ __launch_bounds__(256) void k1_pix(const float* __restrict__ logit,
                                              const float* __restrict__ cw,
                                              uint8_t* __restrict__ predict,
                                              float* __restrict__ wtent) {
    int t = blockIdx.x * 256 + threadIdx.x;   // 524288 threads
    int p0 = t * 4;
    float xx[4][NC];
#pragma unroll
    for (int c = 0; c < NC; ++c) {
        float4 v = *reinterpret_cast<const float4*>(logit + (size_t)c * HWC + p0);
        xx[0][c] = v.x; xx[1][c] = v.y; xx[2][c] = v.z; xx[3][c] = v.w;
    }
    float went[4];
    int ids[4];
#pragma unroll
    for (int e = 0; e < 4; ++e) {
        float m = xx[e][0]; int id = 0;
#pragma unroll
        for (int c = 1; c < NC; ++c) { if (xx[e][c] > m) { m = xx[e][c]; id = c; } }
        float s = 0.f, u = 0.f;
#pragma unroll
        for (int c = 0; c < NC; ++c) {
            float d = xx[e][c] - m;
            float ex = __expf(d);
            s += ex;
            u = fmaf(ex, d, u);
        }
        float ent = __logf(s) - u / s;        // == -sum p*log p  (1e-6 bias ~2e-5, negligible)
        went[e] = ent * cw[id] * INV_LN19;
        ids[e] = id;
    }
    uint32_t packed = (uint32_t)ids[0] | ((uint32_t)ids[1] << 8) |
                      ((uint32_t)ids[2] << 16) | ((uint32_t)ids[3] << 24);
    *reinterpret_cast<uint32_t*>(predict + p0) = packed;
    *reinterpret_cast<float4*>(wtent + p0) = make_float4(went[0], went[1], went[2], went[3]);
}

// ---------------- K2pad: zero the 16-col pads (ws is poisoned each launch) ----------------
__global__ void k2_pad(uint8_t* __restrict__ hist, float* __restrict__ colent) {
    int t = blockIdx.x * 256 + threadIdx.x;   // 20480 threads exactly
    const uint4 z = make_uint4(0u, 0u, 0u, 0u);
    if (t < NC * HH) {
        uint8_t* row = hist + (size_t)t * WP;
        *reinterpret_cast<uint4*>(row) = z;
        *reinterpret_cast<uint4*>(row + 2064) = z;
    } else {
        int r = t - NC * HH;   // 0..1023
        float* row = colent + (size_t)r * WP;
#pragma unroll
        for (int k = 0; k < 4; ++k) {
            *reinterpret_cast<uint4*>(row + 4 * k) = z;
            *reinterpret_cast<uint4*>(row + 2064 + 4 * k) = z;
        }
    }
}

// ---------------- K2: vertical 33-tap sliding window (per-class counts + entropy) ----------
#define SEG 16
__global__ __launch_bounds__(256) void k2_vert(const uint8_t* __restrict__ predict,
                                               const float* __restrict__ wtent,
                                               uint8_t* __restrict__ hist,
                                               float* __restrict__ colent) {
    int w = blockIdx.x * 64 + (threadIdx.x & 63);          // coalesced lane->column
    int seg = blockIdx.y * 4 + (threadIdx.x >> 6);          // 64 segments of 16 rows
    int r0 = seg * SEG;
    int cnt[NC];
#pragma unroll
    for (int c = 0; c < NC; ++c) cnt[c] = 0;
    float es = 0.f;
    for (int h = r0 - RAD; h < r0 + RAD; ++h) {
        if (h >= 0) {
            int pin = predict[(size_t)h * WW + w];
#pragma unroll
            for (int c = 0; c < NC; ++c) cnt[c] += (pin == c);
            es += wtent[(size_t)h * WW + w];
        }
    }
    for (int r = r0; r < r0 + SEG; ++r) {
        int ha = r + RAD;
        if (ha < HH) {
            int pin = predict[(size_t)ha * WW + w];
#pragma unroll
            for (int c = 0; c < NC; ++c) cnt[c] += (pin == c);
            es += wtent[(size_t)ha * WW + w];
        }
        size_t rowoff = (size_t)r * WP + RAD + w;
#pragma unroll
        for (int c = 0; c < NC; ++c)
            hist[(size_t)c * HH * WP + rowoff] = (uint8_t)cnt[c];
        colent[rowoff] = es;
        int hs = r - RAD;
        if (hs >= 0) {
            int pin = predict[(size_t)hs * WW + w];
#pragma unroll
            for (int c = 0; c < NC; ++c) cnt[c] -= (pin == c);
            es -= wtent[(size_t)hs * WW + w];
        }
    }
}

// ---------------- K3: horizontal 33-tap pass, LDS-tiled, impurity + outputs ----------------
#define TR 32     // tile rows
#define TC 128    // tile output cols
__global__ __launch_bounds__(256) void k3_horiz(const uint8_t* __restrict__ hist,
                                                const float* __restrict__ colent,
                                                float* __restrict__ out) {
    __shared__ float smem[TR * 165];                 // 21120 B; reused u8-tile then f32-tile
    uint32_t* smem_u = reinterpret_cast<uint32_t*>(smem);

    int r0 = blockIdx.y * TR;
    int w0 = blockIdx.x * TC;
    int row = threadIdx.x >> 3;     // 0..31
    int seg = threadIdx.x & 7;      // 8 segments x 16 cols
    int r = r0 + row;
    int c0 = seg * 16;
    float nh = (float)(imin(r + RAD, HH - 1) - imax(r - RAD, 0) + 1);
    float rcpN[16], imp[16];
#pragma unroll
    for (int j = 0; j < 16; ++j) {
        int wc = w0 + c0 + j;
        float nw = (float)(imin(wc + RAD, WW - 1) - imax(wc - RAD, 0) + 1);
        rcpN[j] = 1.0f / (nh * nw);
        imp[j] = 0.f;
    }
    for (int c = 0; c < NC; ++c) {
        __syncthreads();
        const uint32_t* src = reinterpret_cast<const uint32_t*>(hist + (size_t)c * HH * WP);
#pragma unroll
        for (int i = 0; i < 5; ++i) {                 // 32 rows x 40 dwords = 1280
            int k = threadIdx.x + i * 256;
            int rr = k / 40, cc = k % 40;
            smem_u[rr * 41 + cc] = src[(size_t)(r0 + rr) * (WP / 4) + (w0 >> 2) + cc];
        }
        __syncthreads();
        const uint32_t* sp = smem_u + row * 41 + (c0 >> 2);
        uint32_t d[12];
#pragma unroll
        for (int k = 0; k < 12; ++k) d[k] = sp[k];
        int run = 0;
#pragma unroll
        for (int k = 0; k < 8; ++k)
            run += (int)(d[k] & 255) + (int)((d[k] >> 8) & 255) +
                   (int)((d[k] >> 16) & 255) + (int)(d[k] >> 24);
#pragma unroll
        for (int j = 0; j < 16; ++j) {
            int ein  = (int)((d[8 + (j >> 2)] >> (8 * (j & 3))) & 255);
            int eout = (int)((d[j >> 2]       >> (8 * (j & 3))) & 255);
            int n = run + ein;
            float dist = (float)n * rcpN[j];
            imp[j] = fmaf(dist, __logf(dist + 1e-6f), imp[j]);
            run = n - eout;
        }
    }
    __syncthreads();
#pragma unroll
    for (int i = 0; i < 20; ++i) {                    // 32 rows x 160 f32 = 5120
        int k = threadIdx.x + i * 256;
        int rr = k / 160, cc = k % 160;
        smem[rr * 165 + cc] = colent[(size_t)(r0 + rr) * WP + w0 + cc];
    }
    __syncthreads();
    const float* ep = smem + row * 165 + c0;
    float erun = 0.f;
#pragma unroll
    for (int k = 0; k < 32; ++k) erun += ep[k];
#pragma unroll
    for (int j = 0; j < 16; ++j) {
        float esum = erun + ep[j + 32];
        float unc = esum * rcpN[j];
        float rim = imp[j] * (-INV_LN19);
        int wc = w0 + c0 + j;
        size_t o = (size_t)r * WW + wc;
        out[o] = rim * unc;          // score
        out[HWC + o] = rim;          // region_impurity
        out[2 * HWC + o] = unc;      // prediction_uncertainty
        erun = esum - ep[j];
    }
}

extern "C" void kernel_launch(void* const* d_in, const int* in_sizes, int n_in,
                              void* d_out, int out_size, void* d_ws, size_t ws_size,
                              hipStream_t stream) {
    const float* logit = (const float*)d_in[0];
    const float* cw = (const float*)d_in[1];
    float* out = (float*)d_out;
    uint8_t* ws = (uint8_t*)d_ws;

    uint8_t* predict = ws;                              //  2 MB  u8 [1024][2048]
    float* wtent = (float*)(ws + 2097152);              //  8 MB  f32 [1024][2048]
    float* colent = (float*)(ws + 10485760);            //  8.5MB f32 [1024][2080] (padded)
    uint8_t* hist = ws + 19005440;                      // 40.5MB u8 [19][1024][2080] (padded)

    k1_pix<<<2048, 256, 0, stream>>>(logit, cw, predict, wtent);
    k2_pad<<<80, 256, 0, stream>>>(hist, colent);
    k2_vert<<<dim3(32, 16), 256, 0, stream>>>(predict, wtent, hist, colent);
    k3_horiz<<<dim3(16, 32), 256, 0, stream>>>(hist, colent, out);
}

// Round 2
// 315.835 us; speedup vs baseline: 1.0625x; 1.0625x over previous
//
#include <hip/hip_runtime.h>
#include <stdint.h>

#define HH 1024
#define WW 2048
#define HWC (HH * WW)
#define NC 19
#define RAD 16
static constexpr float INV_LN19 = 1.0f / 2.9444389791664403f;

static __device__ __forceinline__ int imin(int a, int b) { return a < b ? a : b; }
static __device__ __forceinline__ int imax(int a, int b) { return a > b ? a : b; }

// ---------------- K1: softmax entropy + argmax, 4 pixels/thread ----------------
__global__ __launch_bounds__(256) void k1_pix(const float* __restrict__ logit,
                                              const float* __restrict__ cw,
                                              uint8_t* __restrict__ predict,
                                              float* __restrict__ wtent) {
    int t = blockIdx.x * 256 + threadIdx.x;   // 524288 threads
    int p0 = t * 4;
    float xx[4][NC];
#pragma unroll
    for (int c = 0; c < NC; ++c) {
        float4 v = *reinterpret_cast<const float4*>(logit + (size_t)c * HWC + p0);
        xx[0][c] = v.x; xx[1][c] = v.y; xx[2][c] = v.z; xx[3][c] = v.w;
    }
    float went[4];
    int ids[4];
#pragma unroll
    for (int e = 0; e < 4; ++e) {
        float m = xx[e][0]; int id = 0;
#pragma unroll
        for (int c = 1; c < NC; ++c) { if (xx[e][c] > m) { m = xx[e][c]; id = c; } }
        float s = 0.f, u = 0.f;
#pragma unroll
        for (int c = 0; c < NC; ++c) {
            float d = xx[e][c] - m;
            float ex = __expf(d);
            s += ex;
            u = fmaf(ex, d, u);
        }
        float ent = __logf(s) - u / s;        // == -sum p*log p  (1e-6 bias ~2e-5, negligible)
        went[e] = ent * cw[id] * INV_LN19;
        ids[e] = id;
    }
    uint32_t packed = (uint32_t)ids[0] | ((uint32_t)ids[1] << 8) |
                      ((uint32_t)ids[2] << 16) | ((uint32_t)ids[3] << 24);
    *reinterpret_cast<uint32_t*>(predict + p0) = packed;
    *reinterpret_cast<float4*>(wtent + p0) = make_float4(went[0], went[1], went[2], went[3]);
}

// ---------------- K23: fused vertical+horizontal 33x33 box passes, per-tile in LDS --------
// Tile: 32 output rows x 128 output cols. Input halo tile: 64 rows x 160 cols.
// LDS map (bytes):
//   [     0, 10240)  sp   u8 [64][160]   predict tile (0xFF = out-of-image)
//   [ 10240, 51200)  swt  f32[64][160]   wtent tile (dead after vertical pass)
//   [ 10240, 30720)  sce  f32[32][160]   vertical entropy sums — in-place over swt rows 0..31
//                                        (same stride, read-row-rr-before-write ordering => safe)
//   [ 30720, 51712)  scnt u32[32][164]   per-class vertical counts (overlays dead swt rows 32..63;
//                                        stride 164: bank=(4*rr+16*seg+x)%32 -> <=2-way = free)
#define TR 32
#define TC 128
#define IR 64
#define IC 160
__global__ __launch_bounds__(256) void k23_fused(const uint8_t* __restrict__ predict,
                                                 const float* __restrict__ wtent,
                                                 float* __restrict__ out) {
    __shared__ __align__(16) char smem[51712];
    uint8_t*  sp8  = reinterpret_cast<uint8_t*>(smem);
    uint32_t* sp32 = reinterpret_cast<uint32_t*>(smem);
    float*    swt  = reinterpret_cast<float*>(smem + 10240);
    float*    sce  = swt;
    uint32_t* scnt = reinterpret_cast<uint32_t*>(smem + 30720);

    int tid = threadIdx.x;
    int r0 = blockIdx.y * TR;
    int w0 = blockIdx.x * TC;

    // ---- stage predict tile (dword loads; gcb is 4-aligned so dwords never straddle edge) ----
#pragma unroll
    for (int i = 0; i < 10; ++i) {                 // 2560 dwords
        int k = tid + i * 256;
        int rr = k / 40, cc = k - rr * 40;
        int grow = r0 - RAD + rr;
        int gcb = w0 - RAD + cc * 4;
        uint32_t v = 0xFFFFFFFFu;                  // class 255 = "no class" for OOB
        if ((unsigned)grow < HH && (unsigned)gcb < WW)
            v = *reinterpret_cast<const uint32_t*>(predict + (size_t)grow * WW + gcb);
        sp32[rr * 40 + cc] = v;
    }
    // ---- stage wtent tile ----
#pragma unroll
    for (int i = 0; i < 40; ++i) {                 // 10240 floats
        int k = tid + i * 256;
        int rr = k / 160, cc = k - rr * 160;
        int grow = r0 - RAD + rr;
        int gc = w0 - RAD + cc;
        float v = 0.f;
        if ((unsigned)grow < HH && (unsigned)gc < WW)
            v = wtent[(size_t)grow * WW + gc];
        swt[rr * 160 + cc] = v;
    }
    __syncthreads();

    // ---- vertical 33-tap entropy sum: 160 column threads, sliding window ----
    if (tid < IC) {
        float es = 0.f;
#pragma unroll
        for (int h = 0; h < 32; ++h) es += swt[h * 160 + tid];
        for (int rr = 0; rr < 32; ++rr) {
            float tmp = swt[rr * 160 + tid];       // read row rr BEFORE overwriting it
            es += swt[(rr + 32) * 160 + tid];
            sce[rr * 160 + tid] = es;              // in-place over swt row rr
            es -= tmp;
        }
    }

    // ---- per-thread output geometry ----
    int row = tid >> 3;          // 0..31
    int seg = tid & 7;           // 8 segments x 16 cols
    int c0 = seg * 16;
    int r = r0 + row;
    float nh = (float)(imin(r + RAD, HH - 1) - imax(r - RAD, 0) + 1);
    float rcpN[16], imp[16];
#pragma unroll
    for (int j = 0; j < 16; ++j) {
        int wc = w0 + c0 + j;
        float nw = (float)(imin(wc + RAD, WW - 1) - imax(wc - RAD, 0) + 1);
        rcpN[j] = 1.0f / (nh * nw);
        imp[j] = 0.f;
    }

    // ---- per-class: vertical count slide -> LDS, then horizontal 33-tap slide ----
    for (int c = 0; c < NC; ++c) {
        __syncthreads();                            // also fences swt reads vs scnt writes (c==0)
        if (tid < IC) {
            int cnt = 0;
#pragma unroll
            for (int h = 0; h < 32; ++h) cnt += (sp8[h * 160 + tid] == c);
            for (int rr = 0; rr < 32; ++rr) {
                cnt += (sp8[(rr + 32) * 160 + tid] == c);
                scnt[rr * 164 + tid] = (uint32_t)cnt;
                cnt -= (sp8[rr * 160 + tid] == c);
            }
        }
        __syncthreads();
        const uint32_t* base = scnt + row * 164 + c0;
        int run = 0;
#pragma unroll
        for (int k = 0; k < 32; ++k) run += (int)base[k];
#pragma unroll
        for (int j = 0; j < 16; ++j) {
            int n = run + (int)base[j + 32];
            float dist = (float)n * rcpN[j];
            imp[j] = fmaf(dist, __logf(dist + 1e-6f), imp[j]);
            run = n - (int)base[j];
        }
    }

    // ---- horizontal 33-tap entropy slide + outputs ----
    const float* ep = sce + row * 160 + c0;
    float erun = 0.f;
#pragma unroll
    for (int k = 0; k < 32; ++k) erun += ep[k];
#pragma unroll
    for (int j = 0; j < 16; ++j) {
        float esum = erun + ep[j + 32];
        float unc = esum * rcpN[j];
        float rim = imp[j] * (-INV_LN19);
        int wc = w0 + c0 + j;
        size_t o = (size_t)r * WW + wc;
        out[o] = rim * unc;          // score
        out[HWC + o] = rim;          // region_impurity
        out[2 * HWC + o] = unc;      // prediction_uncertainty
        erun = esum - ep[j];
    }
}

extern "C" void kernel_launch(void* const* d_in, const int* in_sizes, int n_in,
                              void* d_out, int out_size, void* d_ws, size_t ws_size,
                              hipStream_t stream) {
    const float* logit = (const float*)d_in[0];
    const float* cw = (const float*)d_in[1];
    float* out = (float*)d_out;
    uint8_t* ws = (uint8_t*)d_ws;

    uint8_t* predict = ws;                              // 2 MB  u8 [1024][2048]
    float* wtent = (float*)(ws + 2097152);              // 8 MB  f32 [1024][2048]

    k1_pix<<<2048, 256, 0, stream>>>(logit, cw, predict, wtent);
    k23_fused<<<dim3(WW / TC, HH / TR), 256, 0, stream>>>(predict, wtent, out);
}

// Round 3
// 286.711 us; speedup vs baseline: 1.1704x; 1.1016x over previous
//
#include <hip/hip_runtime.h>
#include <stdint.h>

#define HH 1024
#define WW 2048
#define HWC (HH * WW)
#define NC 19
#define RAD 16
#define TR 32
#define TC 128
#define IC 160          // TC + 2*RAD input columns
#define SN 165          // LDS row stride (dwords): bank=(5*row+16*seg+k)%32 -> 2-way = free
static constexpr float INV_LN19 = 1.0f / 2.9444389791664403f;

static __device__ __forceinline__ int imin(int a, int b) { return a < b ? a : b; }
static __device__ __forceinline__ int imax(int a, int b) { return a > b ? a : b; }

// ---------------- K1: softmax entropy + argmax, 4 pixels/thread ----------------
__global__ __launch_bounds__(256) void k1_pix(const float* __restrict__ logit,
                                              const float* __restrict__ cw,
                                              uint8_t* __restrict__ predict,
                                              float* __restrict__ wtent) {
    int t = blockIdx.x * 256 + threadIdx.x;   // 524288 threads
    int p0 = t * 4;
    float xx[4][NC];
#pragma unroll
    for (int c = 0; c < NC; ++c) {
        float4 v = *reinterpret_cast<const float4*>(logit + (size_t)c * HWC + p0);
        xx[0][c] = v.x; xx[1][c] = v.y; xx[2][c] = v.z; xx[3][c] = v.w;
    }
    float went[4];
    int ids[4];
#pragma unroll
    for (int e = 0; e < 4; ++e) {
        float m = xx[e][0]; int id = 0;
#pragma unroll
        for (int c = 1; c < NC; ++c) { if (xx[e][c] > m) { m = xx[e][c]; id = c; } }
        float s = 0.f, u = 0.f;
#pragma unroll
        for (int c = 0; c < NC; ++c) {
            float d = xx[e][c] - m;
            float ex = __expf(d);
            s += ex;
            u = fmaf(ex, d, u);
        }
        float ent = __logf(s) - u / s;        // == -sum p*log p  (1e-6 bias ~2e-5, negligible)
        went[e] = ent * cw[id] * INV_LN19;
        ids[e] = id;
    }
    uint32_t packed = (uint32_t)ids[0] | ((uint32_t)ids[1] << 8) |
                      ((uint32_t)ids[2] << 16) | ((uint32_t)ids[3] << 24);
    *reinterpret_cast<uint32_t*>(predict + p0) = packed;
    *reinterpret_cast<float4*>(wtent + p0) = make_float4(went[0], went[1], went[2], went[3]);
}

// ---------------- K23: fused 33x33 box passes; 4-class packed; conflict-free LDS ----------
// Tile: 32 output rows x 128 output cols. Vertical threads (tid<160) own one input column
// each: predict column cached packed in 16 VGPRs (loaded direct from global, L1/L2-hot),
// wtent column read direct from global. 5 passes x 4 classes (class 19 = dummy, counts 0).
// Vertical counts packed u8x4 per u32; horizontal slide keeps two u16-pair accumulators
// (max 33*33=1089 < 65536, no cross-field carry). Outputs bounce через LDS for coalescing.
__global__ __launch_bounds__(256) void k23_fused(const uint8_t* __restrict__ predict,
                                                 const float* __restrict__ wtent,
                                                 float* __restrict__ out) {
    __shared__ uint32_t s_cnt[TR * SN];   // 21120 B: packed vertical counts; later rim plane
    __shared__ float    s_ce[TR * SN];    // 21120 B: vertical entropy sums; later unc plane
    const uint32_t M = 0x00FF00FFu;

    int tid = threadIdx.x;
    int r0 = blockIdx.y * TR;
    int w0 = blockIdx.x * TC;

    // ---- vertical prep (tid<160): predict column -> 16 packed regs; entropy slide -> s_ce
    uint32_t colreg[16];
    int w = w0 - RAD + tid;
    bool wok = (tid < IC) && ((unsigned)w < WW);
    int wcl = wok ? w : 0;
    if (tid < IC) {
#pragma unroll
        for (int g = 0; g < 16; ++g) {
            uint32_t acc = 0;
#pragma unroll
            for (int b = 0; b < 4; ++b) {
                int grow = r0 - RAD + 4 * g + b;
                bool rok = (unsigned)grow < HH;
                uint32_t pin = (uint32_t)predict[(size_t)(rok ? grow : 0) * WW + wcl];
                if (!(rok && wok)) pin = 255u;
                acc |= pin << (8 * b);
            }
            colreg[g] = acc;
        }
        const float* wp = wtent + wcl;
        float es = 0.f;
#pragma unroll
        for (int h = 0; h < 32; ++h) {
            int grow = r0 - RAD + h;
            if (wok && (unsigned)grow < HH) es += wp[(size_t)grow * WW];
        }
#pragma unroll
        for (int rr = 0; rr < 32; ++rr) {
            int ga = r0 + RAD + rr;
            if (wok && (unsigned)ga < HH) es += wp[(size_t)ga * WW];
            s_ce[rr * SN + tid] = es;
            int gs = r0 - RAD + rr;
            if (wok && (unsigned)gs < HH) es -= wp[(size_t)gs * WW];
        }
    }

    // ---- per-thread output geometry: row = tid&31 (conflict-free LDS), seg = tid>>5
    int row = tid & 31;
    int seg = tid >> 5;
    int c0 = seg * 16;
    int r = r0 + row;
    float nh = (float)(imin(r + RAD, HH - 1) - imax(r - RAD, 0) + 1);
    float rcpN[16], imp[16];
#pragma unroll
    for (int j = 0; j < 16; ++j) {
        int wc = w0 + c0 + j;
        float nw = (float)(imin(wc + RAD, WW - 1) - imax(wc - RAD, 0) + 1);
        rcpN[j] = 1.0f / (nh * nw);
        imp[j] = 0.f;
    }

    // ---- 5 passes x 4 classes ----
    for (int p = 0; p < 5; ++p) {
        __syncthreads();                      // prev pass's reads done before overwriting s_cnt
        if (tid < IC) {
            uint32_t m[32];
            uint32_t cnt = 0;
#pragma unroll
            for (int h = 0; h < 32; ++h) {
                uint32_t pin = (colreg[h >> 2] >> ((h & 3) * 8)) & 255u;
                uint32_t mm = ((int)(pin >> 2) == p) ? (1u << ((pin & 3u) << 3)) : 0u;
                m[h] = mm;
                cnt += mm;
            }
#pragma unroll
            for (int rr = 0; rr < 32; ++rr) {
                int h = rr + 32;
                uint32_t pin = (colreg[h >> 2] >> ((h & 3) * 8)) & 255u;
                uint32_t mm = ((int)(pin >> 2) == p) ? (1u << ((pin & 3u) << 3)) : 0u;
                cnt += mm;
                s_cnt[rr * SN + tid] = cnt;   // packed u8x4 vertical counts (<=33 each)
                cnt -= m[rr];
            }
        }
        __syncthreads();
        const uint32_t* base = s_cnt + row * SN + c0;
        uint32_t cache[16];
        uint32_t lo = 0, hi = 0;              // u16-pairs: lo={b0,b2}, hi={b1,b3}
#pragma unroll
        for (int k = 0; k < 32; ++k) {
            uint32_t v = base[k];
            if (k < 16) cache[k] = v;
            lo += v & M;
            hi += (v >> 8) & M;
        }
#pragma unroll
        for (int j = 0; j < 16; ++j) {
            uint32_t vin = base[j + 32];
            uint32_t nlo = lo + (vin & M);
            uint32_t nhi = hi + ((vin >> 8) & M);
            float n0 = (float)(nlo & 0xFFFFu);
            float n1 = (float)(nhi & 0xFFFFu);
            float n2 = (float)(nlo >> 16);
            float n3 = (float)(nhi >> 16);
            float d0 = n0 * rcpN[j], d1 = n1 * rcpN[j];
            float d2 = n2 * rcpN[j], d3 = n3 * rcpN[j];
            imp[j] = fmaf(d0, __logf(d0 + 1e-6f), imp[j]);
            imp[j] = fmaf(d1, __logf(d1 + 1e-6f), imp[j]);
            imp[j] = fmaf(d2, __logf(d2 + 1e-6f), imp[j]);
            imp[j] = fmaf(d3, __logf(d3 + 1e-6f), imp[j]);
            uint32_t vo = cache[j];
            lo = nlo - (vo & M);
            hi = nhi - ((vo >> 8) & M);
        }
    }

    // ---- horizontal entropy slide (s_ce untouched during passes) ----
    const float* ep = s_ce + row * SN + c0;
    float ecache[16];
    float erun = 0.f;
#pragma unroll
    for (int k = 0; k < 32; ++k) {
        float v = ep[k];
        if (k < 16) ecache[k] = v;
        erun += v;
    }
    float unc[16];
#pragma unroll
    for (int j = 0; j < 16; ++j) {
        float esum = erun + ep[j + 32];
        unc[j] = esum * rcpN[j];
        erun = esum - ecache[j];
    }
    __syncthreads();                          // all s_ce reads complete before overwrite

    // ---- stage result planes in LDS, then fully-coalesced stores ----
    float* rimp = reinterpret_cast<float*>(s_cnt);
#pragma unroll
    for (int j = 0; j < 16; ++j) {
        rimp[row * SN + c0 + j] = imp[j] * (-INV_LN19);
        s_ce[row * SN + c0 + j] = unc[j];
    }
    __syncthreads();
#pragma unroll
    for (int i = 0; i < 16; ++i) {
        int idx = tid + 256 * i;              // 0..4095 over 32x128 tile
        int rr = idx >> 7, cc = idx & 127;
        float rim = rimp[rr * SN + cc];
        float un = s_ce[rr * SN + cc];
        size_t o = (size_t)(r0 + rr) * WW + (w0 + cc);
        out[o] = rim * un;                    // score
        out[HWC + o] = rim;                   // region_impurity
        out[2 * HWC + o] = un;                // prediction_uncertainty
    }
}

extern "C" void kernel_launch(void* const* d_in, const int* in_sizes, int n_in,
                              void* d_out, int out_size, void* d_ws, size_t ws_size,
                              hipStream_t stream) {
    const float* logit = (const float*)d_in[0];
    const float* cw = (const float*)d_in[1];
    float* out = (float*)d_out;
    uint8_t* ws = (uint8_t*)d_ws;

    uint8_t* predict = ws;                              // 2 MB  u8 [1024][2048]
    float* wtent = (float*)(ws + 2097152);              // 8 MB  f32 [1024][2048]

    k1_pix<<<2048, 256, 0, stream>>>(logit, cw, predict, wtent);
    k23_fused<<<dim3(WW / TC, HH / TR), 256, 0, stream>>>(predict, wtent, out);
}